// Round 9
// baseline (1511.794 us; speedup 1.0000x reference)
//
#include <hip/hip_runtime.h>
#include <math.h>

#define N_NODES 100000
#define N_EDGES 1600000
#define HID 128
#define OUTD 47
#define OSTR 48

#define NPB 128                       // nodes per fine bucket
#define NB 782                        // ceil(100000/128)
#define BCAP 2560                     // record capacity per fine bucket (mean 2046, max ~2300)
#define CHUNK 2048                    // edges per phase-A block
#define NCHB 782                      // phase-A binning blocks
#define CWB 64                        // convw blocks appended to binA grid

typedef _Float16 f16x2 __attribute__((ext_vector_type(2)));
typedef _Float16 f16x8 __attribute__((ext_vector_type(8)));
typedef float f32x4 __attribute__((ext_vector_type(4)));

__device__ inline unsigned short f2h(float x) {
    _Float16 h = (_Float16)x;
    return __builtin_bit_cast(unsigned short, h);
}
__device__ inline unsigned int pk2h(float lo, float hi) {
    f16x2 v; v.x = (_Float16)lo; v.y = (_Float16)hi;
    return __builtin_bit_cast(unsigned int, v);
}
__device__ inline float h_lo(unsigned int u) {
    f16x2 v = __builtin_bit_cast(f16x2, u);
    return (float)v.x;
}
__device__ inline float h_hi(unsigned int u) {
    f16x2 v = __builtin_bit_cast(f16x2, u);
    return (float)v.y;
}
__device__ inline unsigned int pkadd(unsigned int a, unsigned int b) {
    f16x2 x = __builtin_bit_cast(f16x2, a);
    f16x2 y = __builtin_bit_cast(f16x2, b);
    x = x + y;                          // v_pk_add_f16
    return __builtin_bit_cast(unsigned int, x);
}

// src-chunk for gather locality: 16 chunks of 6250 nodes
__device__ inline unsigned int src_chunk(unsigned int s) {
    return (s * 42950u) >> 28;   // == s / 6250 for s < 100000
}

// ---------------- Phase A: bin edges by dst fine-bucket + (appended blocks) weight convert ----------------

__global__ __launch_bounds__(256) void binA_k(
    const int* __restrict__ src, const int* __restrict__ dst,
    int* __restrict__ gcur, unsigned int* __restrict__ binned,
    const float* __restrict__ W0, const float* __restrict__ W1, const float* __restrict__ W2,
    unsigned short* __restrict__ Wt0, unsigned short* __restrict__ Wt1,
    unsigned short* __restrict__ Wt2)
{
    __shared__ unsigned int sortedL[CHUNK];
    __shared__ unsigned short bucketOf[CHUNK];
    __shared__ int cntL[NB];
    __shared__ int excL[NB];
    __shared__ int curL[NB];
    __shared__ int gposL[NB];
    __shared__ int partial[256];

    int t = threadIdx.x;

    if (blockIdx.x >= NCHB) {
        int i = (blockIdx.x - NCHB) * 256 + t;
        if (i < 16384) {
            int n = i >> 7, k = i & 127;
            Wt0[i] = f2h(W0[k * 128 + n]);
            Wt1[i] = f2h(W1[k * 128 + n]);
        }
        if (i < 48 * 128) {
            int n = i >> 7, k = i & 127;
            Wt2[i] = (n < OUTD) ? f2h(W2[k * OUTD + n]) : (unsigned short)0;
        }
        return;
    }

    int e0 = blockIdx.x * CHUNK;

    for (int i = t; i < NB; i += 256) cntL[i] = 0;
    __syncthreads();

    for (int i = t; i < CHUNK; i += 256) {
        int e = e0 + i;
        if (e < N_EDGES) atomicAdd(&cntL[dst[e] >> 7], 1);
    }
    __syncthreads();

    int b4 = t * 4;
    int c0 = (b4 + 0 < NB) ? cntL[b4 + 0] : 0;
    int c1 = (b4 + 1 < NB) ? cntL[b4 + 1] : 0;
    int c2 = (b4 + 2 < NB) ? cntL[b4 + 2] : 0;
    int c3 = (b4 + 3 < NB) ? cntL[b4 + 3] : 0;
    int lsum = c0 + c1 + c2 + c3;
    partial[t] = lsum;
    __syncthreads();
    for (int off = 1; off < 256; off <<= 1) {
        int x = (t >= off) ? partial[t - off] : 0;
        __syncthreads();
        partial[t] += x;
        __syncthreads();
    }
    int pbase = partial[t] - lsum;
    if (b4 + 0 < NB) { excL[b4 + 0] = pbase;                curL[b4 + 0] = pbase; }
    if (b4 + 1 < NB) { excL[b4 + 1] = pbase + c0;           curL[b4 + 1] = pbase + c0; }
    if (b4 + 2 < NB) { excL[b4 + 2] = pbase + c0 + c1;      curL[b4 + 2] = pbase + c0 + c1; }
    if (b4 + 3 < NB) { excL[b4 + 3] = pbase + c0 + c1 + c2; curL[b4 + 3] = pbase + c0 + c1 + c2; }
    __syncthreads();

    int tot = partial[255];

    for (int i = t; i < CHUNK; i += 256) {
        int e = e0 + i;
        if (e < N_EDGES) {
            int d = dst[e];
            int s = src[e];
            int bkt = d >> 7;
            int pos = atomicAdd(&curL[bkt], 1);
            sortedL[pos] = ((unsigned int)s << 7) | (unsigned int)(d & 127);
            bucketOf[pos] = (unsigned short)bkt;
        }
    }
    __syncthreads();

    for (int b = t; b < NB; b += 256) {
        int c = cntL[b];
        gposL[b] = c ? atomicAdd(&gcur[b], c) : 0;
    }
    __syncthreads();

    for (int i = t; i < tot; i += 256) {
        unsigned int r = sortedL[i];
        int bkt = bucketOf[i];
        binned[(size_t)bkt * BCAP + gposL[bkt] + (i - excL[bkt])] = r;
    }
}

// ---------------- Phase B: per-fine-bucket CSR finalize into fixed regions ----------------

__global__ __launch_bounds__(256) void binB_k(
    const unsigned int* __restrict__ binned, const int* __restrict__ gcur,
    int2* __restrict__ rowse, float* __restrict__ dinv, int* __restrict__ colv)
{
    __shared__ unsigned int recL[BCAP];
    __shared__ int colL[BCAP];
    __shared__ int hist[2048];
    __shared__ int partial[256];

    int b = blockIdx.x, t = threadIdx.x;
    int cnt = gcur[b];
    int base = b * BCAP;
    const unsigned int* rp = binned + (size_t)b * BCAP;

    for (int i = t; i < 2048; i += 256) hist[i] = 0;
    __syncthreads();

    for (int i = t; i < cnt; i += 256) {
        unsigned int r = rp[i];
        recL[i] = r;
        unsigned int key = ((r & 127u) << 4) | src_chunk(r >> 7);
        atomicAdd(&hist[key], 1);
    }
    __syncthreads();

    int base8 = t * 8;
    int v[8], lsum = 0;
#pragma unroll
    for (int j = 0; j < 8; j++) { v[j] = hist[base8 + j]; lsum += v[j]; }
    partial[t] = lsum;
    __syncthreads();
    for (int off = 1; off < 256; off <<= 1) {
        int x = (t >= off) ? partial[t - off] : 0;
        __syncthreads();
        partial[t] += x;
        __syncthreads();
    }
    int run = partial[t] - lsum;
#pragma unroll
    for (int j = 0; j < 8; j++) { hist[base8 + j] = run; run += v[j]; }
    __syncthreads();

    if (t < NPB) {
        int node = b * NPB + t;
        if (node < N_NODES) {
            int start = hist[t << 4];
            int end = (t < NPB - 1) ? hist[(t + 1) << 4] : cnt;
            rowse[node] = make_int2(base + start, base + end);
            dinv[node] = rsqrtf((float)(end - start + 1));   // +1 self-loop
        }
    }
    __syncthreads();

    for (int i = t; i < cnt; i += 256) {
        unsigned int r = recL[i];
        unsigned int key = ((r & 127u) << 4) | src_chunk(r >> 7);
        int pos = atomicAdd(&hist[key], 1);
        colL[pos] = (int)(r >> 7);
    }
    __syncthreads();
    for (int i = t; i < cnt; i += 256) colv[base + i] = colL[i];
}

// ---------------- MFMA GEMM (M x 128 @ 128 x N), f16, fused BN-final+BN-apply+ReLU, dinv prescale ----------------

template <int AF16, int MODE, int NT, int OF16>
__global__ __launch_bounds__(256) void gemm_k(
    const void* __restrict__ Ap, const unsigned short* __restrict__ Wt,
    const float* __restrict__ bnSum, const float* __restrict__ bnSq,
    const float* __restrict__ gam, const float* __restrict__ bet,
    const float* __restrict__ dinv, void* __restrict__ Outp,
    int ncols, int ostride)
{
    __shared__ unsigned short WtL[NT * 16][136];
    __shared__ float sS[128], sT[128];

    int t = threadIdx.x;
    if (MODE) {
        if (t < 128) {
            float mean = bnSum[t] * (1.0f / N_NODES);
            float var = bnSq[t] * (1.0f / N_NODES) - mean * mean;
            float inv = rsqrtf(var + 1e-5f);
            float s = gam[t] * inv;
            sS[t] = s;
            sT[t] = bet[t] - mean * s;
        }
    }

    const int TOT = NT * 16 * 128;
    for (int e = t * 8; e < TOT; e += 256 * 8) {
        int n = e >> 7, k = e & 127;
        uint4 v = *(const uint4*)(Wt + e);
        *(uint4*)&WtL[n][k] = v;
    }
    __syncthreads();

    int wave = t >> 6, lane = t & 63;
    int quad = lane >> 4, m16 = lane & 15;
    int rbase = blockIdx.x * 128 + wave * 32;

    f32x4 acc[2][NT];
#pragma unroll
    for (int rt = 0; rt < 2; rt++)
#pragma unroll
        for (int ct = 0; ct < NT; ct++) acc[rt][ct] = (f32x4){0.f, 0.f, 0.f, 0.f};

#pragma unroll
    for (int kc = 0; kc < 4; kc++) {
        int kb = kc * 32 + quad * 8;
        f16x8 afrag[2];
#pragma unroll
        for (int rt = 0; rt < 2; rt++) {
            int row = rbase + rt * 16 + m16;
            bool rv = (row < N_NODES);
            if (AF16) {
                uint4 v = make_uint4(0, 0, 0, 0);
                if (rv) v = *(const uint4*)((const unsigned short*)Ap + (size_t)row * 128 + kb);
                if (MODE) {
                    unsigned int uu[4] = {v.x, v.y, v.z, v.w};
                    unsigned int* fp = (unsigned int*)&afrag[rt];
#pragma unroll
                    for (int i = 0; i < 4; i++) {
                        int k0 = kb + 2 * i;
                        float lo = fmaxf(h_lo(uu[i]) * sS[k0] + sT[k0], 0.f);
                        float hi = fmaxf(h_hi(uu[i]) * sS[k0 + 1] + sT[k0 + 1], 0.f);
                        fp[i] = pk2h(lo, hi);
                    }
                } else {
                    afrag[rt] = __builtin_bit_cast(f16x8, v);
                }
            } else {
                const float* ap = (const float*)Ap + (size_t)row * 128 + kb;
                float4 f0 = make_float4(0.f, 0.f, 0.f, 0.f), f1 = f0;
                if (rv) { f0 = *(const float4*)ap; f1 = *(const float4*)(ap + 4); }
                f16x8 a;
                a.s0 = (_Float16)f0.x; a.s1 = (_Float16)f0.y;
                a.s2 = (_Float16)f0.z; a.s3 = (_Float16)f0.w;
                a.s4 = (_Float16)f1.x; a.s5 = (_Float16)f1.y;
                a.s6 = (_Float16)f1.z; a.s7 = (_Float16)f1.w;
                afrag[rt] = a;
            }
        }
#pragma unroll
        for (int ct = 0; ct < NT; ct++) {
            f16x8 bfrag = *(f16x8*)&WtL[ct * 16 + m16][kb];
#pragma unroll
            for (int rt = 0; rt < 2; rt++)
                acc[rt][ct] = __builtin_amdgcn_mfma_f32_16x16x32_f16(
                    afrag[rt], bfrag, acc[rt][ct], 0, 0, 0);
        }
    }

#pragma unroll
    for (int rt = 0; rt < 2; rt++)
#pragma unroll
        for (int r = 0; r < 4; r++) {
            int row = rbase + rt * 16 + quad * 4 + r;
            if (row < N_NODES) {
                float d = dinv[row];
#pragma unroll
                for (int ct = 0; ct < NT; ct++) {
                    int c = ct * 16 + m16;
                    if (c < ncols) {
                        float val = acc[rt][ct][r] * d;
                        if (OF16)
                            ((unsigned short*)Outp)[(size_t)row * ostride + c] = f2h(val);
                        else
                            ((float*)Outp)[(size_t)row * ostride + c] = val;
                    }
                }
            }
        }
}

// ---------------- Aggregation + fused BN stats: one wave per dst node, quarter-wave per record ----------------
// Grid covers exactly N_NODES (25000 blocks x 4 waves) — no partial blocks.

__global__ __launch_bounds__(256) void agg_k(
    const unsigned int* __restrict__ H, const int2* __restrict__ rowse,
    const int* __restrict__ colv, const float* __restrict__ dinv,
    const float* __restrict__ bias, unsigned int* __restrict__ out,
    float* __restrict__ bnSum, float* __restrict__ bnSq)
{
    __shared__ float sumL[128], sqL[128];
    int t = threadIdx.x;
    if (t < 128) { sumL[t] = 0.f; sqL[t] = 0.f; }
    __syncthreads();

    int gw = (blockIdx.x * 256 + t) >> 6;
    int lane = t & 63;
    int q = lane >> 4;             // quarter id: records 4t+q
    int c = lane & 15;             // uint4 index within row (channels 8c..8c+7)
    int2 se = rowse[gw];
    int rp = se.x, re = se.y;
    const uint4* H4 = (const uint4*)H;   // row = 16 uint4 (256 B)

    unsigned int a0 = 0, a1 = 0, a2 = 0, a3 = 0;   // packed f16x2 accumulators
    if (q == 0) {                  // self-loop (prescaled row)
        uint4 u = H4[(size_t)gw * 16 + c];
        a0 = u.x; a1 = u.y; a2 = u.z; a3 = u.w;
    }

    for (int j0 = rp; j0 < re; j0 += 64) {
        int idx = (j0 + lane < re) ? __builtin_nontemporal_load(colv + j0 + lane) : 0;
        int n = min(64, re - j0);
        int nq = n >> 2;           // complete groups of 4 records
        int t4 = 0;
        for (; t4 + 1 < nq; t4 += 2) {
            int sa = __shfl(idx, 4 * t4 + q);
            int sb = __shfl(idx, 4 * t4 + 4 + q);
            uint4 ua = H4[(size_t)sa * 16 + c];
            uint4 ub = H4[(size_t)sb * 16 + c];
            a0 = pkadd(pkadd(a0, ua.x), ub.x);
            a1 = pkadd(pkadd(a1, ua.y), ub.y);
            a2 = pkadd(pkadd(a2, ua.z), ub.z);
            a3 = pkadd(pkadd(a3, ua.w), ub.w);
        }
        if (t4 < nq) {
            int sa = __shfl(idx, 4 * t4 + q);
            uint4 ua = H4[(size_t)sa * 16 + c];
            a0 = pkadd(a0, ua.x);
            a1 = pkadd(a1, ua.y);
            a2 = pkadd(a2, ua.z);
            a3 = pkadd(a3, ua.w);
        }
        int rem = n & 3;           // tail records: quarters 0..rem-1
        if (rem) {
            int sa = __shfl(idx, (n - rem) + q);
            if (q < rem) {
                uint4 ua = H4[(size_t)sa * 16 + c];
                a0 = pkadd(a0, ua.x);
                a1 = pkadd(a1, ua.y);
                a2 = pkadd(a2, ua.z);
                a3 = pkadd(a3, ua.w);
            }
        }
    }

    // combine the four quarter accumulators (packed adds)
    a0 = pkadd(a0, (unsigned int)__shfl_xor((int)a0, 16));
    a0 = pkadd(a0, (unsigned int)__shfl_xor((int)a0, 32));
    a1 = pkadd(a1, (unsigned int)__shfl_xor((int)a1, 16));
    a1 = pkadd(a1, (unsigned int)__shfl_xor((int)a1, 32));
    a2 = pkadd(a2, (unsigned int)__shfl_xor((int)a2, 16));
    a2 = pkadd(a2, (unsigned int)__shfl_xor((int)a2, 32));
    a3 = pkadd(a3, (unsigned int)__shfl_xor((int)a3, 16));
    a3 = pkadd(a3, (unsigned int)__shfl_xor((int)a3, 32));

    if (q == 0) {
        float d = dinv[gw];
        float4 ba = ((const float4*)bias)[2 * c];
        float4 bb = ((const float4*)bias)[2 * c + 1];
        uint4 r;
        r.x = pk2h(h_lo(a0) * d + ba.x, h_hi(a0) * d + ba.y);
        r.y = pk2h(h_lo(a1) * d + ba.z, h_hi(a1) * d + ba.w);
        r.z = pk2h(h_lo(a2) * d + bb.x, h_hi(a2) * d + bb.y);
        r.w = pk2h(h_lo(a3) * d + bb.z, h_hi(a3) * d + bb.w);
        ((uint4*)out)[(size_t)gw * 16 + c] = r;

        // fused BN stats on the stored (f16-rounded) values — what the next gemm reads
        float v0 = h_lo(r.x), v1 = h_hi(r.x), v2 = h_lo(r.y), v3 = h_hi(r.y);
        float v4 = h_lo(r.z), v5 = h_hi(r.z), v6 = h_lo(r.w), v7 = h_hi(r.w);
        int ch = c * 8;
        atomicAdd(&sumL[ch + 0], v0); atomicAdd(&sqL[ch + 0], v0 * v0);
        atomicAdd(&sumL[ch + 1], v1); atomicAdd(&sqL[ch + 1], v1 * v1);
        atomicAdd(&sumL[ch + 2], v2); atomicAdd(&sqL[ch + 2], v2 * v2);
        atomicAdd(&sumL[ch + 3], v3); atomicAdd(&sqL[ch + 3], v3 * v3);
        atomicAdd(&sumL[ch + 4], v4); atomicAdd(&sqL[ch + 4], v4 * v4);
        atomicAdd(&sumL[ch + 5], v5); atomicAdd(&sqL[ch + 5], v5 * v5);
        atomicAdd(&sumL[ch + 6], v6); atomicAdd(&sqL[ch + 6], v6 * v6);
        atomicAdd(&sumL[ch + 7], v7); atomicAdd(&sqL[ch + 7], v7 * v7);
    }
    __syncthreads();
    if (t < 128) {
        atomicAdd(&bnSum[t], sumL[t]);
        atomicAdd(&bnSq[t], sqL[t]);
    }
}

// ---------------- Final aggregation (f16 48-stride rows), quarter-wave + log_softmax ----------------

__global__ __launch_bounds__(256) void agg_out_k(
    const unsigned int* __restrict__ H, const int2* __restrict__ rowse,
    const int* __restrict__ colv, const float* __restrict__ dinv,
    const float* __restrict__ b2, float* __restrict__ out)
{
    int gw = (blockIdx.x * 256 + threadIdx.x) >> 6;
    int lane = threadIdx.x & 63;
    if (gw >= N_NODES) return;
    int q = lane >> 4;
    int c = lane & 15;
    bool ld = c < 12;              // 12 uint2 = 48 f16 per row
    int2 se = rowse[gw];
    int rp = se.x, re = se.y;
    const uint2* H2 = (const uint2*)H;   // row = 12 uint2 (96 B)

    unsigned int a0 = 0, a1 = 0;   // packed f16x2 accumulators (4 channels)
    if (q == 0 && ld) {
        uint2 u = H2[(size_t)gw * 12 + c];   // self (prescaled)
        a0 = u.x; a1 = u.y;
    }

    for (int j0 = rp; j0 < re; j0 += 64) {
        int idx = (j0 + lane < re) ? __builtin_nontemporal_load(colv + j0 + lane) : 0;
        int n = min(64, re - j0);
        int nq = n >> 2;
        int t4 = 0;
        for (; t4 + 1 < nq; t4 += 2) {
            int sa = __shfl(idx, 4 * t4 + q);
            int sb = __shfl(idx, 4 * t4 + 4 + q);
            if (ld) {
                uint2 ua = H2[(size_t)sa * 12 + c];
                uint2 ub = H2[(size_t)sb * 12 + c];
                a0 = pkadd(pkadd(a0, ua.x), ub.x);
                a1 = pkadd(pkadd(a1, ua.y), ub.y);
            }
        }
        if (t4 < nq) {
            int sa = __shfl(idx, 4 * t4 + q);
            if (ld) {
                uint2 ua = H2[(size_t)sa * 12 + c];
                a0 = pkadd(a0, ua.x);
                a1 = pkadd(a1, ua.y);
            }
        }
        int rem = n & 3;
        if (rem) {
            int sa = __shfl(idx, (n - rem) + q);
            if (q < rem && ld) {
                uint2 ua = H2[(size_t)sa * 12 + c];
                a0 = pkadd(a0, ua.x);
                a1 = pkadd(a1, ua.y);
            }
        }
    }

    a0 = pkadd(a0, (unsigned int)__shfl_xor((int)a0, 16));
    a0 = pkadd(a0, (unsigned int)__shfl_xor((int)a0, 32));
    a1 = pkadd(a1, (unsigned int)__shfl_xor((int)a1, 16));
    a1 = pkadd(a1, (unsigned int)__shfl_xor((int)a1, 32));

    float d = dinv[gw];
    int ch = c * 4;
    float v0 = -INFINITY, v1 = -INFINITY, v2 = -INFINITY, v3 = -INFINITY;
    if (ld) {
        v0 = h_lo(a0) * d + b2[ch];
        v1 = h_hi(a0) * d + b2[ch + 1];
        v2 = h_lo(a1) * d + b2[ch + 2];
        if (ch + 3 < OUTD) v3 = h_hi(a1) * d + b2[ch + 3];
    }
    float m = fmaxf(fmaxf(v0, v1), fmaxf(v2, v3));
    m = fmaxf(m, __shfl_xor(m, 1));
    m = fmaxf(m, __shfl_xor(m, 2));
    m = fmaxf(m, __shfl_xor(m, 4));
    m = fmaxf(m, __shfl_xor(m, 8));
    float e = 0.f;
    if (ld) {
        e = __expf(v0 - m) + __expf(v1 - m) + __expf(v2 - m);
        if (ch + 3 < OUTD) e += __expf(v3 - m);
    }
    float sum = e;
    sum += __shfl_xor(sum, 1);
    sum += __shfl_xor(sum, 2);
    sum += __shfl_xor(sum, 4);
    sum += __shfl_xor(sum, 8);
    float ls = logf(sum);
    if (q == 0 && ld) {
        float* op = out + (size_t)gw * OUTD + ch;
        op[0] = v0 - m - ls;
        op[1] = v1 - m - ls;
        op[2] = v2 - m - ls;
        if (ch + 3 < OUTD) op[3] = v3 - m - ls;
    }
}

// ---------------- launch ----------------

extern "C" void kernel_launch(void* const* d_in, const int* in_sizes, int n_in,
                              void* d_out, int out_size, void* d_ws, size_t ws_size,
                              hipStream_t stream)
{
    const float* x   = (const float*)d_in[0];
    const int*   ei  = (const int*)d_in[1];
    const float* W0  = (const float*)d_in[2];
    const float* b0  = (const float*)d_in[3];
    const float* W1  = (const float*)d_in[4];
    const float* b1  = (const float*)d_in[5];
    const float* W2  = (const float*)d_in[6];
    const float* b2  = (const float*)d_in[7];
    const float* g0  = (const float*)d_in[8];
    const float* be0 = (const float*)d_in[9];
    const float* g1  = (const float*)d_in[10];
    const float* be1 = (const float*)d_in[11];
    const int* srcv = ei;
    const int* dstv = ei + N_EDGES;

    char* w = (char*)d_ws;
    unsigned int* H0 = (unsigned int*)w;  w += (size_t)N_NODES * 128 * 2;   // f16 [N][128]
    unsigned int* H1 = (unsigned int*)w;  w += (size_t)N_NODES * 128 * 2;   // f16 [N][128]
    unsigned int* Hf = (unsigned int*)w;  w += (size_t)N_NODES * OSTR * 2;  // f16 [N][48]
    unsigned int* binned = (unsigned int*)w; w += (size_t)NB * BCAP * 4;    // 8.0 MB
    int* colv = (int*)w;        w += (size_t)NB * BCAP * 4;                 // 8.0 MB (fixed regions)
    unsigned short* Wt0 = (unsigned short*)w; w += 16384 * 2;
    unsigned short* Wt1 = (unsigned short*)w; w += 16384 * 2;
    unsigned short* Wt2 = (unsigned short*)w; w += 48 * 128 * 2;
    int2* rowse = (int2*)w;     w += (size_t)N_NODES * 8;
    float* dinv = (float*)w;    w += (size_t)N_NODES * 4;
    // single-memset region: gcur (784 ints) + bnS0,bnQ0,bnS1,bnQ1 (512 floats)
    int* gcur = (int*)w;        w += 784 * 4;
    float* bnS0 = (float*)w;    w += 128 * 4;
    float* bnQ0 = (float*)w;    w += 128 * 4;
    float* bnS1 = (float*)w;    w += 128 * 4;
    float* bnQ1 = (float*)w;    w += 128 * 4;

    int gb = (N_NODES + 127) / 128;       // 782
    int ab = (N_NODES * 64 + 255) / 256;  // 25000 (exactly N_NODES waves)

    hipMemsetAsync(gcur, 0, (784 + 512) * 4, stream);

    binA_k<<<NCHB + CWB, 256, 0, stream>>>(srcv, dstv, gcur, binned,
                                           W0, W1, W2, Wt0, Wt1, Wt2);
    binB_k<<<NB, 256, 0, stream>>>(binned, gcur, rowse, dinv, colv);

    // Layer 0: x fp32 -> H0 f16 (dinv-prescaled)
    gemm_k<0, 0, 8, 1><<<gb, 256, 0, stream>>>(x, Wt0, nullptr, nullptr, nullptr, nullptr,
                                               dinv, H0, 128, 128);
    agg_k<<<ab, 256, 0, stream>>>(H0, rowse, colv, dinv, b0, H1, bnS0, bnQ0);

    // Layer 1: BN-final+BN-apply+ReLU fused into gemm, f16 MFMA
    gemm_k<1, 1, 8, 1><<<gb, 256, 0, stream>>>(H1, Wt1, bnS0, bnQ0, g0, be0,
                                               dinv, H0, 128, 128);
    agg_k<<<ab, 256, 0, stream>>>(H0, rowse, colv, dinv, b1, H1, bnS1, bnQ1);

    // Layer 2: 47-wide out (f16, stride 48) + fused log_softmax aggregation
    gemm_k<1, 1, 3, 1><<<gb, 256, 0, stream>>>(H1, Wt2, bnS1, bnQ1, g1, be1,
                                               dinv, Hf, OUTD, OSTR);
    agg_out_k<<<ab, 256, 0, stream>>>(Hf, rowse, colv, dinv, b2, (float*)d_out);
}